// Round 1
// baseline (237.384 us; speedup 1.0000x reference)
//
#include <hip/hip_runtime.h>

// TernaryDense: out[N,U] = inputs[N,D] @ ternarize(w[D,U])
//   ternarize(w) = round(clip(w,-1,1)) with round-half-to-even
//                = sign(w) if |w| > 0.5 else 0      (exact equivalence)
// N=8192, D=4096, U=4096, all f32.
//
// Strategy: ternary weights are sparse in {-1,0,1}. Scan w once, record a
// per-128-column-block "has any nonzero" flag in d_ws. GEMM blocks whose
// column block is all-zero write exact zeros (the dominant, mandatory
// 134 MB output write) and skip the matmul. Blocks with nonzeros run a
// correct dense f32 SGEMM fallback with on-the-fly ternarization (CDNA4 has
// no fp32 MFMA; the fallback is VALU FMA based).

#define N_DIM 8192
#define D_DIM 4096
#define U_DIM 4096
#define BM 128
#define BN 128
#define BK 8
#define NUM_COL_BLOCKS (U_DIM / BN)   // 32

__global__ void tz_init_flags(int* __restrict__ flags) {
    int i = threadIdx.x;
    if (i < NUM_COL_BLOCKS) flags[i] = 0;
}

// Grid-stride scan over w (as float4). Sets flags[col/128] if any ternarized
// weight in that column block is nonzero. 128 % 4 == 0 so each float4 stays
// within one column block.
__global__ __launch_bounds__(256) void tz_scan(const float* __restrict__ w,
                                               int* __restrict__ flags) {
    const int total4 = (D_DIM * U_DIM) / 4;
    int idx = blockIdx.x * blockDim.x + threadIdx.x;
    int stride = gridDim.x * blockDim.x;
    const float4* w4 = reinterpret_cast<const float4*>(w);
    for (int i = idx; i < total4; i += stride) {
        float4 v = w4[i];
        bool nz = (fabsf(v.x) > 0.5f) || (fabsf(v.y) > 0.5f) ||
                  (fabsf(v.z) > 0.5f) || (fabsf(v.w) > 0.5f);
        if (nz) {
            int col = (i * 4) % U_DIM;          // first column of this float4
            atomicOr(&flags[col / BN], 1);
        }
    }
}

__device__ __forceinline__ float ternarize(float x) {
    // round-half-to-even of clip(x,-1,1): zero iff |x| <= 0.5
    return (fabsf(x) > 0.5f) ? copysignf(1.0f, x) : 0.0f;
}

__global__ __launch_bounds__(256) void tz_gemm(const float* __restrict__ A,
                                               const float* __restrict__ W,
                                               const int* __restrict__ flags,
                                               float* __restrict__ out) {
    const int bn = blockIdx.x;   // column block (0..31)
    const int bm = blockIdx.y;   // row block    (0..63)
    const int t  = threadIdx.x;

    if (flags[bn] == 0) {
        // Entire 128-wide column stripe of ternarized W is zero -> this
        // 128x128 output tile is exactly zero. Coalesced float4 zero-fill.
        float4 z = make_float4(0.0f, 0.0f, 0.0f, 0.0f);
        float4* outt = reinterpret_cast<float4*>(
            out + (size_t)bm * BM * U_DIM + (size_t)bn * BN);
        const int row_stride4 = U_DIM / 4;      // 1024 float4 per output row
        int c4 = t & 31;                        // float4 column within tile
        int r0 = t >> 5;                        // starting row (0..7)
        #pragma unroll
        for (int r = 0; r < BM; r += 8) {
            outt[(size_t)(r + r0) * row_stride4 + c4] = z;
        }
        return;
    }

    // ---- dense fallback: f32 SGEMM with on-the-fly ternarization ----
    __shared__ float As[BK][BM];   // [k][m]
    __shared__ float Bs[BK][BN];   // [k][n], ternarized

    float acc[8][8];
    #pragma unroll
    for (int i = 0; i < 8; ++i)
        #pragma unroll
        for (int j = 0; j < 8; ++j) acc[i][j] = 0.0f;

    const int tm = (t >> 4) * 8;   // this thread's row offset in tile
    const int tn = (t & 15) * 8;   // this thread's col offset in tile

    const float* Ab = A + (size_t)bm * BM * D_DIM;
    const float* Wb = W + (size_t)bn * BN;

    // A-load mapping: 128 rows x BK cols; 2 threads per row, 4 floats each.
    const int a_row = t >> 1;
    const int a_k0  = (t & 1) * 4;
    // B-load mapping: BK rows x 128 cols; thread -> (kk = t/32, n0 = (t%32)*4)
    const int b_kk = t >> 5;
    const int b_n0 = (t & 31) * 4;

    for (int k0 = 0; k0 < D_DIM; k0 += BK) {
        // stage A tile (transposed into [k][m])
        float4 av = *reinterpret_cast<const float4*>(
            Ab + (size_t)a_row * D_DIM + k0 + a_k0);
        As[a_k0 + 0][a_row] = av.x;
        As[a_k0 + 1][a_row] = av.y;
        As[a_k0 + 2][a_row] = av.z;
        As[a_k0 + 3][a_row] = av.w;
        // stage + ternarize B tile
        float4 bv = *reinterpret_cast<const float4*>(
            Wb + (size_t)(k0 + b_kk) * U_DIM + b_n0);
        Bs[b_kk][b_n0 + 0] = ternarize(bv.x);
        Bs[b_kk][b_n0 + 1] = ternarize(bv.y);
        Bs[b_kk][b_n0 + 2] = ternarize(bv.z);
        Bs[b_kk][b_n0 + 3] = ternarize(bv.w);
        __syncthreads();

        #pragma unroll
        for (int k = 0; k < BK; ++k) {
            float a[8], b[8];
            #pragma unroll
            for (int i = 0; i < 8; ++i) a[i] = As[k][tm + i];
            #pragma unroll
            for (int j = 0; j < 8; ++j) b[j] = Bs[k][tn + j];
            #pragma unroll
            for (int i = 0; i < 8; ++i)
                #pragma unroll
                for (int j = 0; j < 8; ++j) acc[i][j] += a[i] * b[j];
        }
        __syncthreads();
    }

    #pragma unroll
    for (int i = 0; i < 8; ++i) {
        float* orow = out + (size_t)(bm * BM + tm + i) * U_DIM + bn * BN + tn;
        #pragma unroll
        for (int j = 0; j < 8; ++j) orow[j] = acc[i][j];
    }
}

extern "C" void kernel_launch(void* const* d_in, const int* in_sizes, int n_in,
                              void* d_out, int out_size, void* d_ws, size_t ws_size,
                              hipStream_t stream) {
    const float* inputs = (const float*)d_in[0];   // [N, D] f32
    const float* w      = (const float*)d_in[1];   // [D, U] f32
    float* out          = (float*)d_out;           // [N, U] f32
    int* flags          = (int*)d_ws;              // 32 ints

    // 1) zero the column-block flags (d_ws is poisoned 0xAA before each run)
    tz_init_flags<<<1, 64, 0, stream>>>(flags);

    // 2) scan + ternarize w, mark nonzero column blocks
    tz_scan<<<2048, 256, 0, stream>>>(w, flags);

    // 3) GEMM: zero-fill tiles in all-zero column stripes, dense otherwise
    dim3 grid(U_DIM / BN, N_DIM / BM);
    tz_gemm<<<grid, 256, 0, stream>>>(inputs, w, flags, out);
}